// Round 21
// baseline (78.573 us; speedup 1.0000x reference)
//
#include <hip/hip_runtime.h>
#include <math.h>

#define BB 4
#define HH 512
#define LL 4096
#define NN 32
#define DMOUT 512

typedef __attribute__((ext_vector_type(8))) short short8;
typedef __attribute__((ext_vector_type(4))) float f32x4;

__device__ __forceinline__ unsigned f2bf(float x) {
    unsigned u = __float_as_uint(x);
    return (u + 0x7fffu + ((u >> 16) & 1u)) >> 16;
}
__device__ __forceinline__ unsigned packhl(float x) {
    unsigned hb = f2bf(x);
    float xh = __uint_as_float(hb << 16);
    return (hb << 16) | f2bf(x - xh);
}
__device__ __forceinline__ float reconhl(unsigned v) {
    return __uint_as_float(v & 0xffff0000u) + __uint_as_float(v << 16);
}
__device__ __forceinline__ float gelu_fast(float y) {
    float s2 = y * fmaf(y * y, 0.044715f, 1.0f) * 1.5957691216057308f;
    return y * (1.0f / (1.0f + __expf(-s2)));
}
__device__ __forceinline__ void gload_lds16(const void* g, void* l) {
    __builtin_amdgcn_global_load_lds((const __attribute__((address_space(1))) void*)g,
                                     (__attribute__((address_space(3))) void*)l, 16, 0, 0);
}

// ---------------- Kernel P: per-h tables (A3t, Et) + W->bf16 (fused wsplit) ----------------
__global__ __launch_bounds__(256) void prep_kernel(
    const float* __restrict__ log_dt,
    const float* __restrict__ A_re, const float* __restrict__ A_im,
    const float* __restrict__ B_re, const float* __restrict__ B_im,
    const float* __restrict__ C_re, const float* __restrict__ C_im,
    const float* __restrict__ W,
    unsigned* __restrict__ A3t, unsigned* __restrict__ Et,
    unsigned short* __restrict__ whi, int preW) {
    const int h = blockIdx.x;
    const int tid = threadIdx.x;
    __shared__ float cst_lds[256];

    if (preW) {
        int i = (h * 256 + tid) * 4;
        float4 wv = *(const float4*)(W + i);
        ushort4 o;
        o.x = (unsigned short)f2bf(wv.x);
        o.y = (unsigned short)f2bf(wv.y);
        o.z = (unsigned short)f2bf(wv.z);
        o.w = (unsigned short)f2bf(wv.w);
        *(ushort4*)(whi + i) = o;
    }

    if (tid < 32) {
        int n = tid;
        float dt = expf(log_dt[h]);
        float ar = A_re[h * NN + n], ai = A_im[h * NN + n];
        float dtar = dt * ar, dtai = dt * ai;
        float ea = expf(dtar);
        float s, c; sincosf(dtai, &s, &c);
        float dA_r = ea * c, dA_i = ea * s;
        float em_r = dA_r - 1.0f, em_i = dA_i;
        float inv = 1.0f / (ar * ar + ai * ai);
        float t_r = (em_r * ar + em_i * ai) * inv;
        float t_i = (em_i * ar - em_r * ai) * inv;
        float br = B_re[h * NN + n], bi = B_im[h * NN + n];
        cst_lds[0 * 32 + n] = dtar;
        cst_lds[1 * 32 + n] = dtai;
        cst_lds[2 * 32 + n] = dA_r;
        cst_lds[3 * 32 + n] = dA_i;
        cst_lds[4 * 32 + n] = t_r * br - t_i * bi;
        cst_lds[5 * 32 + n] = t_r * bi + t_i * br;
        cst_lds[6 * 32 + n] = 2.0f * C_re[h * NN + n];
        cst_lds[7 * 32 + n] = 2.0f * C_im[h * NN + n];
    }
    __syncthreads();

    const int n = tid & 31, q = tid >> 5;
    const float dtar = cst_lds[0 * 32 + n], dtai = cst_lds[1 * 32 + n];
    const float dAr = cst_lds[2 * 32 + n], dAi = cst_lds[3 * 32 + n];
    const float dbr = cst_lds[4 * 32 + n], dbi = cst_lds[5 * 32 + n];
    const float tcr = cst_lds[6 * 32 + n], tci = cst_lds[7 * 32 + n];

    {
        float p = (float)(56 - q * 8);
        float mr = expf(p * dtar);
        float s, c; sincosf(p * dtai, &s, &c);
        float pr = mr * c, pi = mr * s;
        unsigned* base = A3t + (size_t)h * 4096;
#pragma unroll
        for (int jj = 7; jj >= 0; jj--) {
            int m = q * 8 + jj;
            base[m * 64 + n]      = packhl(dbr * pr - dbi * pi);
            base[m * 64 + 32 + n] = packhl(dbr * pi + dbi * pr);
            float nr2 = pr * dAr - pi * dAi;
            pi = pr * dAi + pi * dAr;
            pr = nr2;
        }
    }
    {
        float p = (float)(q * 8 + 1);
        float mr = expf(p * dtar);
        float s, c; sincosf(p * dtai, &s, &c);
        float pr = mr * c, pi = mr * s;
        unsigned* base = Et + (size_t)h * 4096;
#pragma unroll
        for (int i = q * 8; i <= q * 8 + 7; i++) {
            base[i * 64 + n]      = packhl(tcr * pr - tci * pi);
            base[i * 64 + 32 + n] = packhl(-(tcr * pi + tci * pr));
            float nr2 = pr * dAr - pi * dAi;
            pi = pr * dAi + pi * dAr;
            pr = nr2;
        }
    }
}

// ---------------- Kernel B: SSM conv via MFMA; 2 batches per block ----------------
__global__ __launch_bounds__(256, 4) void ssm_kernel(
    const float* __restrict__ u, const float* __restrict__ log_dt,
    const float* __restrict__ A_re, const float* __restrict__ A_im,
    const float* __restrict__ B_re, const float* __restrict__ B_im,
    const float* __restrict__ C_re, const float* __restrict__ C_im,
    const float* __restrict__ D,
    const unsigned* __restrict__ A3t, const unsigned* __restrict__ Et,
    unsigned short* __restrict__ yhi) {
    const int h = blockIdx.x;
    const int b0 = blockIdx.y * 2;
    const int tid = threadIdx.x;
    const int lane = tid & 63;
    const int w = tid >> 6;
    const int g = lane >> 4;
    const int l15 = lane & 15;

    __shared__ unsigned short uh[64 * 72];
    __shared__ unsigned short ul[64 * 72];
    __shared__ unsigned XsR[64 * 36];
    __shared__ unsigned XsI[64 * 36];
    __shared__ unsigned karr_pk[128];
    __shared__ float kpart[256];
    __shared__ float cst_lds[256];

    if (tid < 32) {
        int n = tid;
        float dt = expf(log_dt[h]);
        float ar = A_re[h * NN + n], ai = A_im[h * NN + n];
        float dtar = dt * ar, dtai = dt * ai;
        float ea = expf(dtar);
        float s, c; sincosf(dtai, &s, &c);
        float dA_r = ea * c, dA_i = ea * s;
        float em_r = dA_r - 1.0f, em_i = dA_i;
        float inv = 1.0f / (ar * ar + ai * ai);
        float t_r = (em_r * ar + em_i * ai) * inv;
        float t_i = (em_i * ar - em_r * ai) * inv;
        float br = B_re[h * NN + n], bi = B_im[h * NN + n];
        cst_lds[0 * 32 + n] = dtar;
        cst_lds[1 * 32 + n] = dtai;
        cst_lds[2 * 32 + n] = dA_r;
        cst_lds[3 * 32 + n] = dA_i;
        cst_lds[4 * 32 + n] = t_r * br - t_i * bi;
        cst_lds[5 * 32 + n] = t_r * bi + t_i * br;
        cst_lds[6 * 32 + n] = 2.0f * C_re[h * NN + n];
        cst_lds[7 * 32 + n] = 2.0f * C_im[h * NN + n];
    }
    __syncthreads();   // S0

    short8 a3h0, a3l0, a3h1, a3l1;
    {
        int nprime = w * 16 + l15;
        const unsigned* a3b = A3t + (size_t)h * 4096 + nprime;
#pragma unroll
        for (int j = 0; j < 8; j++) {
            unsigned v = a3b[(g * 8 + j) * 64];
            a3h0[j] = (short)(v >> 16); a3l0[j] = (short)(v & 0xffffu);
            unsigned v2 = a3b[(32 + g * 8 + j) * 64];
            a3h1[j] = (short)(v2 >> 16); a3l1[j] = (short)(v2 & 0xffffu);
        }
    }
    short8 e0h, e0l, e1h, e1l;
    {
        int i = w * 16 + l15;
        const unsigned* eb = Et + (size_t)h * 4096 + i * 64;
#pragma unroll
        for (int j = 0; j < 8; j++) {
            int n = g * 8 + j;
            unsigned v = eb[n];
            e0h[j] = (short)(v >> 16); e0l[j] = (short)(v & 0xffffu);
            unsigned v2 = eb[32 + n];
            e1h[j] = (short)(v2 >> 16); e1l[j] = (short)(v2 & 0xffffu);
        }
    }
    float Mr = 0.f, Mi = 0.f;
    if (tid < 32) {
        int n = tid;
        float dtar = cst_lds[0 * 32 + n], dtai = cst_lds[1 * 32 + n];
        float mr = expf(64.0f * dtar);
        float s, c; sincosf(64.0f * dtai, &s, &c);
        Mr = mr * c; Mi = mr * s;
    }
    {
        int j = tid & 63, nr = tid >> 6;
        float acc = 0.0f;
        if (j == 0) {
#pragma unroll
            for (int q = 0; q < 8; q++) {
                int n = nr * 8 + q;
                acc = fmaf(cst_lds[6 * 32 + n], cst_lds[4 * 32 + n], acc);
                acc = fmaf(-cst_lds[7 * 32 + n], cst_lds[5 * 32 + n], acc);
            }
        } else {
            const unsigned* eb = Et + (size_t)h * 4096 + (j - 1) * 64;
#pragma unroll
            for (int q = 0; q < 8; q++) {
                int n = nr * 8 + q;
                acc = fmaf(reconhl(eb[n]), cst_lds[4 * 32 + n], acc);
                acc = fmaf(reconhl(eb[32 + n]), cst_lds[5 * 32 + n], acc);
            }
        }
        kpart[nr * 64 + j] = acc;
    }
    __syncthreads();   // S1

    if (tid >= 64 && tid < 128) {
        int j = tid - 64;
        float k = kpart[j] + kpart[64 + j] + kpart[128 + j] + kpart[192 + j];
        karr_pk[64 + j] = packhl(k);
    } else if (tid >= 128 && tid < 192) {
        karr_pk[tid - 128] = 0u;
    }
    const float Dh = D[h];

    for (int bb = 0; bb < 2; bb++) {
        const int b = b0 + bb;
        {
            const float* urow = u + ((size_t)(b * HH + h)) * LL;
#pragma unroll
            for (int r = 0; r < 4; r++) {
                int f = tid + 256 * r;
                float4 v = *(const float4*)(urow + f * 4);
                int t = f >> 4, mb = (f & 15) << 2;
                unsigned hx = f2bf(v.x), hy = f2bf(v.y), hz = f2bf(v.z), hw = f2bf(v.w);
                uint2 hwv;
                hwv.x = hx | (hy << 16);
                hwv.y = hz | (hw << 16);
                float rx = v.x - __uint_as_float(hx << 16);
                float ry = v.y - __uint_as_float(hy << 16);
                float rz = v.z - __uint_as_float(hz << 16);
                float rw = v.w - __uint_as_float(hw << 16);
                uint2 lwv;
                lwv.x = f2bf(rx) | (f2bf(ry) << 16);
                lwv.y = f2bf(rz) | (f2bf(rw) << 16);
                *(uint2*)(&uh[t * 72 + mb]) = hwv;
                *(uint2*)(&ul[t * 72 + mb]) = lwv;
            }
        }
        __syncthreads();   // u ready

        {
            int nprime2 = w * 16 + g * 4;
#pragma unroll
            for (int ni = 0; ni < 4; ni++) {
                int t = ni * 16 + l15;
                short8 uH0 = *(const short8*)(uh + t * 72 + g * 8);
                short8 uL0 = *(const short8*)(ul + t * 72 + g * 8);
                short8 uH1 = *(const short8*)(uh + t * 72 + 32 + g * 8);
                short8 uL1 = *(const short8*)(ul + t * 72 + 32 + g * 8);
                f32x4 a = (f32x4){0.f, 0.f, 0.f, 0.f};
                a = __builtin_amdgcn_mfma_f32_16x16x32_bf16(a3h0, uH0, a, 0, 0, 0);
                a = __builtin_amdgcn_mfma_f32_16x16x32_bf16(a3l0, uH0, a, 0, 0, 0);
                a = __builtin_amdgcn_mfma_f32_16x16x32_bf16(a3h0, uL0, a, 0, 0, 0);
                a = __builtin_amdgcn_mfma_f32_16x16x32_bf16(a3h1, uH1, a, 0, 0, 0);
                a = __builtin_amdgcn_mfma_f32_16x16x32_bf16(a3l1, uH1, a, 0, 0, 0);
                a = __builtin_amdgcn_mfma_f32_16x16x32_bf16(a3h1, uL1, a, 0, 0, 0);
                uint4 wv;
                wv.x = __float_as_uint(a[0]); wv.y = __float_as_uint(a[1]);
                wv.z = __float_as_uint(a[2]); wv.w = __float_as_uint(a[3]);
                if (nprime2 < 32) *(uint4*)(&XsR[t * 36 + nprime2]) = wv;
                else              *(uint4*)(&XsI[t * 36 + (nprime2 - 32)]) = wv;
            }
        }
        __syncthreads();   // F ready

        if (tid < 32) {
            int n = tid;
            float cr = 0.f, ci = 0.f;
            unsigned* pR = XsR + n;
            unsigned* pI = XsI + n;
            float fr = __uint_as_float(pR[0]);
            float fi2 = __uint_as_float(pI[0]);
#pragma unroll 4
            for (int t = 0; t < 64; t++) {
                float frn = 0.f, fin = 0.f;
                if (t < 63) { frn = __uint_as_float(pR[(t + 1) * 36]); fin = __uint_as_float(pI[(t + 1) * 36]); }
                pR[t * 36] = packhl(cr);
                pI[t * 36] = packhl(ci);
                float nr = fmaf(Mr, cr, fmaf(-Mi, ci, fr));
                float nic = fmaf(Mr, ci, fmaf(Mi, cr, fi2));
                cr = nr; ci = nic;
                fr = frn; fi2 = fin;
            }
        }
        __syncthreads();   // state ready

        {
            int i = w * 16 + l15;
            short8 kh0, kl0, kh1, kl1;
#pragma unroll
            for (int j = 0; j < 8; j++) {
                unsigned v0 = karr_pk[64 + i - (g * 8 + j)];
                kh0[j] = (short)(v0 >> 16); kl0[j] = (short)(v0 & 0xffffu);
                unsigned v1 = karr_pk[64 + i - (32 + g * 8 + j)];
                kh1[j] = (short)(v1 >> 16); kl1[j] = (short)(v1 & 0xffffu);
            }
            unsigned short* orow = yhi + ((size_t)(b * HH + h)) * LL;
#pragma unroll
            for (int ni = 0; ni < 4; ni++) {
                int t = ni * 16 + l15;
                short8 uH0 = *(const short8*)(uh + t * 72 + g * 8);
                short8 uL0 = *(const short8*)(ul + t * 72 + g * 8);
                short8 uH1 = *(const short8*)(uh + t * 72 + 32 + g * 8);
                short8 uL1 = *(const short8*)(ul + t * 72 + 32 + g * 8);
                uint4 r0 = *(const uint4*)(&XsR[t * 36 + g * 8]);
                uint4 r1 = *(const uint4*)(&XsR[t * 36 + g * 8 + 4]);
                uint4 i0 = *(const uint4*)(&XsI[t * 36 + g * 8]);
                uint4 i1 = *(const uint4*)(&XsI[t * 36 + g * 8 + 4]);
                short8 xrh, xrl, xih, xil;
                xrh[0] = (short)(r0.x >> 16); xrl[0] = (short)(r0.x & 0xffffu);
                xrh[1] = (short)(r0.y >> 16); xrl[1] = (short)(r0.y & 0xffffu);
                xrh[2] = (short)(r0.z >> 16); xrl[2] = (short)(r0.z & 0xffffu);
                xrh[3] = (short)(r0.w >> 16); xrl[3] = (short)(r0.w & 0xffffu);
                xrh[4] = (short)(r1.x >> 16); xrl[4] = (short)(r1.x & 0xffffu);
                xrh[5] = (short)(r1.y >> 16); xrl[5] = (short)(r1.y & 0xffffu);
                xrh[6] = (short)(r1.z >> 16); xrl[6] = (short)(r1.z & 0xffffu);
                xrh[7] = (short)(r1.w >> 16); xrl[7] = (short)(r1.w & 0xffffu);
                xih[0] = (short)(i0.x >> 16); xil[0] = (short)(i0.x & 0xffffu);
                xih[1] = (short)(i0.y >> 16); xil[1] = (short)(i0.y & 0xffffu);
                xih[2] = (short)(i0.z >> 16); xil[2] = (short)(i0.z & 0xffffu);
                xih[3] = (short)(i0.w >> 16); xil[3] = (short)(i0.w & 0xffffu);
                xih[4] = (short)(i1.x >> 16); xil[4] = (short)(i1.x & 0xffffu);
                xih[5] = (short)(i1.y >> 16); xil[5] = (short)(i1.y & 0xffffu);
                xih[6] = (short)(i1.z >> 16); xil[6] = (short)(i1.z & 0xffffu);
                xih[7] = (short)(i1.w >> 16); xil[7] = (short)(i1.w & 0xffffu);
                f32x4 a = (f32x4){0.f, 0.f, 0.f, 0.f};
                a = __builtin_amdgcn_mfma_f32_16x16x32_bf16(kh0, uH0, a, 0, 0, 0);
                a = __builtin_amdgcn_mfma_f32_16x16x32_bf16(kl0, uH0, a, 0, 0, 0);
                a = __builtin_amdgcn_mfma_f32_16x16x32_bf16(kh0, uL0, a, 0, 0, 0);
                a = __builtin_amdgcn_mfma_f32_16x16x32_bf16(kh1, uH1, a, 0, 0, 0);
                a = __builtin_amdgcn_mfma_f32_16x16x32_bf16(kl1, uH1, a, 0, 0, 0);
                a = __builtin_amdgcn_mfma_f32_16x16x32_bf16(kh1, uL1, a, 0, 0, 0);
                a = __builtin_amdgcn_mfma_f32_16x16x32_bf16(e0h, xrh, a, 0, 0, 0);
                a = __builtin_amdgcn_mfma_f32_16x16x32_bf16(e0h, xrl, a, 0, 0, 0);
                a = __builtin_amdgcn_mfma_f32_16x16x32_bf16(e0l, xrh, a, 0, 0, 0);
                a = __builtin_amdgcn_mfma_f32_16x16x32_bf16(e1h, xih, a, 0, 0, 0);
                a = __builtin_amdgcn_mfma_f32_16x16x32_bf16(e1h, xil, a, 0, 0, 0);
                a = __builtin_amdgcn_mfma_f32_16x16x32_bf16(e1l, xih, a, 0, 0, 0);
                ushort4 ov;
                unsigned short* op = &ov.x;
#pragma unroll
                for (int r = 0; r < 4; r++) {
                    int io = w * 16 + g * 4 + r;
                    float uv = __uint_as_float(((unsigned)uh[t * 72 + io]) << 16)
                             + __uint_as_float(((unsigned)ul[t * 72 + io]) << 16);
                    float y = a[r] + Dh * uv;
                    op[r] = (unsigned short)f2bf(gelu_fast(y));
                }
                *(ushort4*)(&orow[t * 64 + w * 16 + g * 4]) = ov;
            }
        }
        __syncthreads();
    }
}

// ---------------- Kernel C: MFMA bf16 GEMM 64l x 128d, dbuf; mi=8 for Y-frag reuse ----------------
__global__ __launch_bounds__(256) void gemm_glu_mfma(const unsigned short* __restrict__ yhi,
                                                     const float* __restrict__ W,
                                                     const unsigned short* __restrict__ whi,
                                                     const float* __restrict__ bias,
                                                     float* __restrict__ out, int preW) {
    const int b = blockIdx.z;
    const int d0 = blockIdx.y * 128;
    const int l0 = blockIdx.x * 64;
    const int tid = threadIdx.x;
    const int lane = tid & 63;
    const int wid = tid >> 6;
    const int wave_n = wid & 1;    // 32-l half
    const int wave_mb = wid >> 1;  // 64-d half
    const int l15 = lane & 15;
    const int g = lane >> 4;

    __shared__ unsigned short Ysh[2][32 * 64];   // 2 x 4 KB
    __shared__ char Wlds[2][256 * 64];           // 2 x 16 KB (rows 0..127 z1, 128..255 z2)

    f32x4 acc[8][2];
#pragma unroll
    for (int i = 0; i < 8; i++)
#pragma unroll
        for (int j = 0; j < 2; j++) acc[i][j] = (f32x4){0.f, 0.f, 0.f, 0.f};

#define STAGE(BUF, KT)                                                                   \
    {                                                                                    \
        const int h0s = (KT) * 32;                                                       \
        {                                                                                \
            int kr = tid >> 3;                                                           \
            int cc = tid & 7;                                                            \
            int scol = (cc * 8) ^ ((kr & 8) ? 8 : 0);                                    \
            const unsigned short* srcY = yhi + ((size_t)(b * HH + h0s + kr)) * LL + l0 + scol; \
            gload_lds16(srcY, (char*)Ysh[BUF] + tid * 16);                               \
        }                                                                                \
        if (preW) {                                                                      \
            _Pragma("unroll")                                                            \
            for (int e = 0; e < 4; e++) {                                                \
                int c = e * 256 + tid;                                                   \
                int row = c >> 2;                                                        \
                int gx = c & 3;                                                          \
                int qq = (row >> 1) & 3;                                                 \
                int grow = (row < 128) ? (d0 + row) : (384 + d0 + row);                  \
                const unsigned short* srcW = whi + (size_t)grow * 512 + h0s + ((gx ^ qq) * 8); \
                gload_lds16(srcW, Wlds[BUF] + c * 16);                                   \
            }                                                                            \
        } else {                                                                         \
            _Pragma("unroll")                                                            \
            for (int e = 0; e < 2; e++) {                                                \
                int c = e * 256 + tid;                                                   \
                int row = c >> 1;                                                        \
                int kb = (c & 1) * 16;                                                   \
                int qq = (row >> 1) & 3;                                                 \
                int grow = (row < 128) ? (d0 + row) : (384 + d0 + row);                  \
                const float* srcW = W + (size_t)grow * 512 + h0s + kb;                   \
                float4 w0 = *(const float4*)(srcW);                                      \
                float4 w1 = *(const float4*)(srcW + 4);                                  \
                float4 w2 = *(const float4*)(srcW + 8);                                  \
                float4 w3 = *(const float4*)(srcW + 12);                                 \
                short8 v0, v1;                                                           \
                v0[0] = (short)f2bf(w0.x); v0[1] = (short)f2bf(w0.y);                    \
                v0[2] = (short)f2bf(w0.z); v0[3] = (short)f2bf(w0.w);                    \
                v0[4] = (short)f2bf(w1.x); v0[5] = (short)f2bf(w1.y);                    \
                v0[6] = (short)f2bf(w1.z); v0[7] = (short)f2bf(w1.w);                    \
                v1[0] = (short)f2bf(w2.x); v1[1] = (short)f2bf(w2.y);                    \
                v1[2] = (short)f2bf(w2.z); v1[3] = (short)f2bf(w2.w);                    \
                v1[4] = (short)f2bf(w3.x); v1[5] = (short)f2bf(w3.y);                    \
                v1[6] = (short)f2bf(w3.z); v1[7] = (short)f2bf(w3.w);                    \
                int g0 = kb >> 3;                                                        \
                *(short8*)(Wlds[BUF] + row * 64 + ((g0 ^ qq) * 16)) = v0;                \
                *(short8*)(Wlds[BUF] + row * 64 + (((g0 + 1) ^ qq) * 16)) = v1;          \
            }                                                                            \
        }                                                                                \
    }

    STAGE(0, 0)
    __syncthreads();

    int cur = 0;
    for (int kt = 0; kt < 16; kt++) {
        if (kt < 15) STAGE(cur ^ 1, kt + 1)

        short8 af[8];
#pragma unroll
        for (int mi = 0; mi < 8; mi++) {
            // mi 0..3: z1 rows; mi 4..7: z2 rows (matched d range)
            int rowb = (mi < 4) ? (wave_mb * 64 + mi * 16) : (128 + wave_mb * 64 + (mi - 4) * 16);
            int row = rowb + l15;
            int qq = (row >> 1) & 3;
            af[mi] = *(const short8*)(Wlds[cur] + row * 64 + ((g ^ qq) * 16));
        }
#pragma unroll
        for (int ni = 0; ni < 2; ni++) {
            int col = wave_n * 32 + ni * 16 + l15;
            int cs = col ^ ((g & 1) << 3);
            const unsigned short* yb = Ysh[cur] + (8 * g) * 64 + cs;
            short8 bh;
            bh[0] = (short)yb[0 * 64];
            bh[1] = (short)yb[1 * 64];
            bh[2] = (short)yb[2 * 64];
            bh[3] = (short)yb[3 * 64];
            bh[4] = (short)yb[4 * 64];
            bh[5] = (short)yb[5 * 64];
            bh[6] = (short)yb[6 * 64];
            bh[7] = (short)yb[7 * 64];
#pragma unroll
            for (int mi = 0; mi < 8; mi++) {
                acc[mi][ni] = __builtin_amdgcn_mfma_f32_16x16x32_bf16(af[mi], bh, acc[mi][ni], 0, 0, 0);
            }
        }
        __syncthreads();
        cur ^= 1;
    }
#undef STAGE

#pragma unroll
    for (int mi = 0; mi < 4; mi++) {
        int dbase = d0 + wave_mb * 64 + mi * 16 + (g << 2);
#pragma unroll
        for (int r = 0; r < 4; r++) {
            int d = dbase + r;
            float b1 = bias[d], b2 = bias[DMOUT + d];
#pragma unroll
            for (int ni = 0; ni < 2; ni++) {
                int l = l0 + wave_n * 32 + ni * 16 + l15;
                float z1 = acc[mi][ni][r] + b1;
                float z2 = acc[mi + 4][ni][r] + b2;
                out[((size_t)(b * DMOUT + d)) * LL + l] = z1 * (1.0f / (1.0f + __expf(-z2)));
            }
        }
    }
}

extern "C" void kernel_launch(void* const* d_in, const int* in_sizes, int n_in,
                              void* d_out, int out_size, void* d_ws, size_t ws_size,
                              hipStream_t stream) {
    const float* u      = (const float*)d_in[0];
    const float* log_dt = (const float*)d_in[1];
    const float* A_re   = (const float*)d_in[2];
    const float* A_im   = (const float*)d_in[3];
    const float* B_re   = (const float*)d_in[4];
    const float* B_im   = (const float*)d_in[5];
    const float* C_re   = (const float*)d_in[6];
    const float* C_im   = (const float*)d_in[7];
    const float* D      = (const float*)d_in[8];
    const float* W      = (const float*)d_in[9];
    const float* bias   = (const float*)d_in[10];
    float* out = (float*)d_out;

    char* ws = (char*)d_ws;
    unsigned short* yhi = (unsigned short*)ws;                     // 16,777,216 B
    unsigned* A3t = (unsigned*)(ws + 16777216);                    //  8,388,608 B
    unsigned* Et  = (unsigned*)(ws + 16777216 + 8388608);          //  8,388,608 B
    unsigned short* whi = (unsigned short*)(ws + 33554432);        //  1,048,576 B (total 34.6 MB)
    int preW = (ws_size >= (size_t)(33554432 + 1048576)) ? 1 : 0;

    prep_kernel<<<HH, 256, 0, stream>>>(log_dt, A_re, A_im, B_re, B_im, C_re, C_im,
                                        W, A3t, Et, whi, preW);
    ssm_kernel<<<dim3(HH, BB / 2), 256, 0, stream>>>(u, log_dt, A_re, A_im, B_re, B_im,
                                                     C_re, C_im, D, A3t, Et, yhi);
    gemm_glu_mfma<<<dim3(64, 4, BB), 256, 0, stream>>>(yhi, W, whi, bias, out, preW);
}

// Round 22
// 75.778 us; speedup vs baseline: 1.0369x; 1.0369x over previous
//
#include <hip/hip_runtime.h>
#include <math.h>

#define BB 4
#define HH 512
#define LL 4096
#define NN 32
#define DMOUT 512

typedef __attribute__((ext_vector_type(8))) short short8;
typedef __attribute__((ext_vector_type(4))) float f32x4;

__device__ __forceinline__ unsigned f2bf(float x) {
    unsigned u = __float_as_uint(x);
    return (u + 0x7fffu + ((u >> 16) & 1u)) >> 16;
}
__device__ __forceinline__ unsigned packhl(float x) {
    unsigned hb = f2bf(x);
    float xh = __uint_as_float(hb << 16);
    return (hb << 16) | f2bf(x - xh);
}
__device__ __forceinline__ float reconhl(unsigned v) {
    return __uint_as_float(v & 0xffff0000u) + __uint_as_float(v << 16);
}
__device__ __forceinline__ float gelu_fast(float y) {
    float s2 = y * fmaf(y * y, 0.044715f, 1.0f) * 1.5957691216057308f;
    return y * (1.0f / (1.0f + __expf(-s2)));
}
__device__ __forceinline__ void gload_lds16(const void* g, void* l) {
    __builtin_amdgcn_global_load_lds((const __attribute__((address_space(1))) void*)g,
                                     (__attribute__((address_space(3))) void*)l, 16, 0, 0);
}

// ---------------- Kernel P: per-h tables (A3t, Et) + W->bf16 (fused wsplit) ----------------
__global__ __launch_bounds__(256) void prep_kernel(
    const float* __restrict__ log_dt,
    const float* __restrict__ A_re, const float* __restrict__ A_im,
    const float* __restrict__ B_re, const float* __restrict__ B_im,
    const float* __restrict__ C_re, const float* __restrict__ C_im,
    const float* __restrict__ W,
    unsigned* __restrict__ A3t, unsigned* __restrict__ Et,
    unsigned short* __restrict__ whi, int preW) {
    const int h = blockIdx.x;
    const int tid = threadIdx.x;
    __shared__ float cst_lds[256];

    if (preW) {
        int i = (h * 256 + tid) * 4;
        float4 wv = *(const float4*)(W + i);
        ushort4 o;
        o.x = (unsigned short)f2bf(wv.x);
        o.y = (unsigned short)f2bf(wv.y);
        o.z = (unsigned short)f2bf(wv.z);
        o.w = (unsigned short)f2bf(wv.w);
        *(ushort4*)(whi + i) = o;
    }

    if (tid < 32) {
        int n = tid;
        float dt = expf(log_dt[h]);
        float ar = A_re[h * NN + n], ai = A_im[h * NN + n];
        float dtar = dt * ar, dtai = dt * ai;
        float ea = expf(dtar);
        float s, c; sincosf(dtai, &s, &c);
        float dA_r = ea * c, dA_i = ea * s;
        float em_r = dA_r - 1.0f, em_i = dA_i;
        float inv = 1.0f / (ar * ar + ai * ai);
        float t_r = (em_r * ar + em_i * ai) * inv;
        float t_i = (em_i * ar - em_r * ai) * inv;
        float br = B_re[h * NN + n], bi = B_im[h * NN + n];
        cst_lds[0 * 32 + n] = dtar;
        cst_lds[1 * 32 + n] = dtai;
        cst_lds[2 * 32 + n] = dA_r;
        cst_lds[3 * 32 + n] = dA_i;
        cst_lds[4 * 32 + n] = t_r * br - t_i * bi;
        cst_lds[5 * 32 + n] = t_r * bi + t_i * br;
        cst_lds[6 * 32 + n] = 2.0f * C_re[h * NN + n];
        cst_lds[7 * 32 + n] = 2.0f * C_im[h * NN + n];
    }
    __syncthreads();

    const int n = tid & 31, q = tid >> 5;
    const float dtar = cst_lds[0 * 32 + n], dtai = cst_lds[1 * 32 + n];
    const float dAr = cst_lds[2 * 32 + n], dAi = cst_lds[3 * 32 + n];
    const float dbr = cst_lds[4 * 32 + n], dbi = cst_lds[5 * 32 + n];
    const float tcr = cst_lds[6 * 32 + n], tci = cst_lds[7 * 32 + n];

    {
        float p = (float)(56 - q * 8);
        float mr = expf(p * dtar);
        float s, c; sincosf(p * dtai, &s, &c);
        float pr = mr * c, pi = mr * s;
        unsigned* base = A3t + (size_t)h * 4096;
#pragma unroll
        for (int jj = 7; jj >= 0; jj--) {
            int m = q * 8 + jj;
            base[m * 64 + n]      = packhl(dbr * pr - dbi * pi);
            base[m * 64 + 32 + n] = packhl(dbr * pi + dbi * pr);
            float nr2 = pr * dAr - pi * dAi;
            pi = pr * dAi + pi * dAr;
            pr = nr2;
        }
    }
    {
        float p = (float)(q * 8 + 1);
        float mr = expf(p * dtar);
        float s, c; sincosf(p * dtai, &s, &c);
        float pr = mr * c, pi = mr * s;
        unsigned* base = Et + (size_t)h * 4096;
#pragma unroll
        for (int i = q * 8; i <= q * 8 + 7; i++) {
            base[i * 64 + n]      = packhl(tcr * pr - tci * pi);
            base[i * 64 + 32 + n] = packhl(-(tcr * pi + tci * pr));
            float nr2 = pr * dAr - pi * dAi;
            pi = pr * dAi + pi * dAr;
            pr = nr2;
        }
    }
}

// ---------------- Kernel B: SSM conv via MFMA; 2 batches per block ----------------
__global__ __launch_bounds__(256, 4) void ssm_kernel(
    const float* __restrict__ u, const float* __restrict__ log_dt,
    const float* __restrict__ A_re, const float* __restrict__ A_im,
    const float* __restrict__ B_re, const float* __restrict__ B_im,
    const float* __restrict__ C_re, const float* __restrict__ C_im,
    const float* __restrict__ D,
    const unsigned* __restrict__ A3t, const unsigned* __restrict__ Et,
    unsigned short* __restrict__ yhi) {
    const int h = blockIdx.x;
    const int b0 = blockIdx.y * 2;
    const int tid = threadIdx.x;
    const int lane = tid & 63;
    const int w = tid >> 6;
    const int g = lane >> 4;
    const int l15 = lane & 15;

    __shared__ unsigned short uh[64 * 72];
    __shared__ unsigned short ul[64 * 72];
    __shared__ unsigned XsR[64 * 36];
    __shared__ unsigned XsI[64 * 36];
    __shared__ unsigned karr_pk[128];
    __shared__ float kpart[256];
    __shared__ float cst_lds[256];

    if (tid < 32) {
        int n = tid;
        float dt = expf(log_dt[h]);
        float ar = A_re[h * NN + n], ai = A_im[h * NN + n];
        float dtar = dt * ar, dtai = dt * ai;
        float ea = expf(dtar);
        float s, c; sincosf(dtai, &s, &c);
        float dA_r = ea * c, dA_i = ea * s;
        float em_r = dA_r - 1.0f, em_i = dA_i;
        float inv = 1.0f / (ar * ar + ai * ai);
        float t_r = (em_r * ar + em_i * ai) * inv;
        float t_i = (em_i * ar - em_r * ai) * inv;
        float br = B_re[h * NN + n], bi = B_im[h * NN + n];
        cst_lds[0 * 32 + n] = dtar;
        cst_lds[1 * 32 + n] = dtai;
        cst_lds[2 * 32 + n] = dA_r;
        cst_lds[3 * 32 + n] = dA_i;
        cst_lds[4 * 32 + n] = t_r * br - t_i * bi;
        cst_lds[5 * 32 + n] = t_r * bi + t_i * br;
        cst_lds[6 * 32 + n] = 2.0f * C_re[h * NN + n];
        cst_lds[7 * 32 + n] = 2.0f * C_im[h * NN + n];
    }
    __syncthreads();   // S0

    short8 a3h0, a3l0, a3h1, a3l1;
    {
        int nprime = w * 16 + l15;
        const unsigned* a3b = A3t + (size_t)h * 4096 + nprime;
#pragma unroll
        for (int j = 0; j < 8; j++) {
            unsigned v = a3b[(g * 8 + j) * 64];
            a3h0[j] = (short)(v >> 16); a3l0[j] = (short)(v & 0xffffu);
            unsigned v2 = a3b[(32 + g * 8 + j) * 64];
            a3h1[j] = (short)(v2 >> 16); a3l1[j] = (short)(v2 & 0xffffu);
        }
    }
    short8 e0h, e0l, e1h, e1l;
    {
        int i = w * 16 + l15;
        const unsigned* eb = Et + (size_t)h * 4096 + i * 64;
#pragma unroll
        for (int j = 0; j < 8; j++) {
            int n = g * 8 + j;
            unsigned v = eb[n];
            e0h[j] = (short)(v >> 16); e0l[j] = (short)(v & 0xffffu);
            unsigned v2 = eb[32 + n];
            e1h[j] = (short)(v2 >> 16); e1l[j] = (short)(v2 & 0xffffu);
        }
    }
    float Mr = 0.f, Mi = 0.f;
    if (tid < 32) {
        int n = tid;
        float dtar = cst_lds[0 * 32 + n], dtai = cst_lds[1 * 32 + n];
        float mr = expf(64.0f * dtar);
        float s, c; sincosf(64.0f * dtai, &s, &c);
        Mr = mr * c; Mi = mr * s;
    }
    {
        int j = tid & 63, nr = tid >> 6;
        float acc = 0.0f;
        if (j == 0) {
#pragma unroll
            for (int q = 0; q < 8; q++) {
                int n = nr * 8 + q;
                acc = fmaf(cst_lds[6 * 32 + n], cst_lds[4 * 32 + n], acc);
                acc = fmaf(-cst_lds[7 * 32 + n], cst_lds[5 * 32 + n], acc);
            }
        } else {
            const unsigned* eb = Et + (size_t)h * 4096 + (j - 1) * 64;
#pragma unroll
            for (int q = 0; q < 8; q++) {
                int n = nr * 8 + q;
                acc = fmaf(reconhl(eb[n]), cst_lds[4 * 32 + n], acc);
                acc = fmaf(reconhl(eb[32 + n]), cst_lds[5 * 32 + n], acc);
            }
        }
        kpart[nr * 64 + j] = acc;
    }
    __syncthreads();   // S1

    if (tid >= 64 && tid < 128) {
        int j = tid - 64;
        float k = kpart[j] + kpart[64 + j] + kpart[128 + j] + kpart[192 + j];
        karr_pk[64 + j] = packhl(k);
    } else if (tid >= 128 && tid < 192) {
        karr_pk[tid - 128] = 0u;
    }
    const float Dh = D[h];

    for (int bb = 0; bb < 2; bb++) {
        const int b = b0 + bb;
        {
            const float* urow = u + ((size_t)(b * HH + h)) * LL;
#pragma unroll
            for (int r = 0; r < 4; r++) {
                int f = tid + 256 * r;
                float4 v = *(const float4*)(urow + f * 4);
                int t = f >> 4, mb = (f & 15) << 2;
                unsigned hx = f2bf(v.x), hy = f2bf(v.y), hz = f2bf(v.z), hw = f2bf(v.w);
                uint2 hwv;
                hwv.x = hx | (hy << 16);
                hwv.y = hz | (hw << 16);
                float rx = v.x - __uint_as_float(hx << 16);
                float ry = v.y - __uint_as_float(hy << 16);
                float rz = v.z - __uint_as_float(hz << 16);
                float rw = v.w - __uint_as_float(hw << 16);
                uint2 lwv;
                lwv.x = f2bf(rx) | (f2bf(ry) << 16);
                lwv.y = f2bf(rz) | (f2bf(rw) << 16);
                *(uint2*)(&uh[t * 72 + mb]) = hwv;
                *(uint2*)(&ul[t * 72 + mb]) = lwv;
            }
        }
        __syncthreads();   // u ready

        {
            int nprime2 = w * 16 + g * 4;
#pragma unroll
            for (int ni = 0; ni < 4; ni++) {
                int t = ni * 16 + l15;
                short8 uH0 = *(const short8*)(uh + t * 72 + g * 8);
                short8 uL0 = *(const short8*)(ul + t * 72 + g * 8);
                short8 uH1 = *(const short8*)(uh + t * 72 + 32 + g * 8);
                short8 uL1 = *(const short8*)(ul + t * 72 + 32 + g * 8);
                f32x4 a = (f32x4){0.f, 0.f, 0.f, 0.f};
                a = __builtin_amdgcn_mfma_f32_16x16x32_bf16(a3h0, uH0, a, 0, 0, 0);
                a = __builtin_amdgcn_mfma_f32_16x16x32_bf16(a3l0, uH0, a, 0, 0, 0);
                a = __builtin_amdgcn_mfma_f32_16x16x32_bf16(a3h0, uL0, a, 0, 0, 0);
                a = __builtin_amdgcn_mfma_f32_16x16x32_bf16(a3h1, uH1, a, 0, 0, 0);
                a = __builtin_amdgcn_mfma_f32_16x16x32_bf16(a3l1, uH1, a, 0, 0, 0);
                a = __builtin_amdgcn_mfma_f32_16x16x32_bf16(a3h1, uL1, a, 0, 0, 0);
                uint4 wv;
                wv.x = __float_as_uint(a[0]); wv.y = __float_as_uint(a[1]);
                wv.z = __float_as_uint(a[2]); wv.w = __float_as_uint(a[3]);
                if (nprime2 < 32) *(uint4*)(&XsR[t * 36 + nprime2]) = wv;
                else              *(uint4*)(&XsI[t * 36 + (nprime2 - 32)]) = wv;
            }
        }
        __syncthreads();   // F ready

        if (tid < 32) {
            int n = tid;
            float cr = 0.f, ci = 0.f;
            unsigned* pR = XsR + n;
            unsigned* pI = XsI + n;
            float fr = __uint_as_float(pR[0]);
            float fi2 = __uint_as_float(pI[0]);
#pragma unroll 4
            for (int t = 0; t < 64; t++) {
                float frn = 0.f, fin = 0.f;
                if (t < 63) { frn = __uint_as_float(pR[(t + 1) * 36]); fin = __uint_as_float(pI[(t + 1) * 36]); }
                pR[t * 36] = packhl(cr);
                pI[t * 36] = packhl(ci);
                float nr = fmaf(Mr, cr, fmaf(-Mi, ci, fr));
                float nic = fmaf(Mr, ci, fmaf(Mi, cr, fi2));
                cr = nr; ci = nic;
                fr = frn; fi2 = fin;
            }
        }
        __syncthreads();   // state ready

        {
            int i = w * 16 + l15;
            short8 kh0, kl0, kh1, kl1;
#pragma unroll
            for (int j = 0; j < 8; j++) {
                unsigned v0 = karr_pk[64 + i - (g * 8 + j)];
                kh0[j] = (short)(v0 >> 16); kl0[j] = (short)(v0 & 0xffffu);
                unsigned v1 = karr_pk[64 + i - (32 + g * 8 + j)];
                kh1[j] = (short)(v1 >> 16); kl1[j] = (short)(v1 & 0xffffu);
            }
            unsigned short* orow = yhi + ((size_t)(b * HH + h)) * LL;
#pragma unroll
            for (int ni = 0; ni < 4; ni++) {
                int t = ni * 16 + l15;
                short8 uH0 = *(const short8*)(uh + t * 72 + g * 8);
                short8 uL0 = *(const short8*)(ul + t * 72 + g * 8);
                short8 uH1 = *(const short8*)(uh + t * 72 + 32 + g * 8);
                short8 uL1 = *(const short8*)(ul + t * 72 + 32 + g * 8);
                uint4 r0 = *(const uint4*)(&XsR[t * 36 + g * 8]);
                uint4 r1 = *(const uint4*)(&XsR[t * 36 + g * 8 + 4]);
                uint4 i0 = *(const uint4*)(&XsI[t * 36 + g * 8]);
                uint4 i1 = *(const uint4*)(&XsI[t * 36 + g * 8 + 4]);
                short8 xrh, xrl, xih, xil;
                xrh[0] = (short)(r0.x >> 16); xrl[0] = (short)(r0.x & 0xffffu);
                xrh[1] = (short)(r0.y >> 16); xrl[1] = (short)(r0.y & 0xffffu);
                xrh[2] = (short)(r0.z >> 16); xrl[2] = (short)(r0.z & 0xffffu);
                xrh[3] = (short)(r0.w >> 16); xrl[3] = (short)(r0.w & 0xffffu);
                xrh[4] = (short)(r1.x >> 16); xrl[4] = (short)(r1.x & 0xffffu);
                xrh[5] = (short)(r1.y >> 16); xrl[5] = (short)(r1.y & 0xffffu);
                xrh[6] = (short)(r1.z >> 16); xrl[6] = (short)(r1.z & 0xffffu);
                xrh[7] = (short)(r1.w >> 16); xrl[7] = (short)(r1.w & 0xffffu);
                xih[0] = (short)(i0.x >> 16); xil[0] = (short)(i0.x & 0xffffu);
                xih[1] = (short)(i0.y >> 16); xil[1] = (short)(i0.y & 0xffffu);
                xih[2] = (short)(i0.z >> 16); xil[2] = (short)(i0.z & 0xffffu);
                xih[3] = (short)(i0.w >> 16); xil[3] = (short)(i0.w & 0xffffu);
                xih[4] = (short)(i1.x >> 16); xil[4] = (short)(i1.x & 0xffffu);
                xih[5] = (short)(i1.y >> 16); xil[5] = (short)(i1.y & 0xffffu);
                xih[6] = (short)(i1.z >> 16); xil[6] = (short)(i1.z & 0xffffu);
                xih[7] = (short)(i1.w >> 16); xil[7] = (short)(i1.w & 0xffffu);
                f32x4 a = (f32x4){0.f, 0.f, 0.f, 0.f};
                a = __builtin_amdgcn_mfma_f32_16x16x32_bf16(kh0, uH0, a, 0, 0, 0);
                a = __builtin_amdgcn_mfma_f32_16x16x32_bf16(kl0, uH0, a, 0, 0, 0);
                a = __builtin_amdgcn_mfma_f32_16x16x32_bf16(kh0, uL0, a, 0, 0, 0);
                a = __builtin_amdgcn_mfma_f32_16x16x32_bf16(kh1, uH1, a, 0, 0, 0);
                a = __builtin_amdgcn_mfma_f32_16x16x32_bf16(kl1, uH1, a, 0, 0, 0);
                a = __builtin_amdgcn_mfma_f32_16x16x32_bf16(kh1, uL1, a, 0, 0, 0);
                a = __builtin_amdgcn_mfma_f32_16x16x32_bf16(e0h, xrh, a, 0, 0, 0);
                a = __builtin_amdgcn_mfma_f32_16x16x32_bf16(e0h, xrl, a, 0, 0, 0);
                a = __builtin_amdgcn_mfma_f32_16x16x32_bf16(e0l, xrh, a, 0, 0, 0);
                a = __builtin_amdgcn_mfma_f32_16x16x32_bf16(e1h, xih, a, 0, 0, 0);
                a = __builtin_amdgcn_mfma_f32_16x16x32_bf16(e1h, xil, a, 0, 0, 0);
                a = __builtin_amdgcn_mfma_f32_16x16x32_bf16(e1l, xih, a, 0, 0, 0);
                ushort4 ov;
                unsigned short* op = &ov.x;
#pragma unroll
                for (int r = 0; r < 4; r++) {
                    int io = w * 16 + g * 4 + r;
                    float uv = __uint_as_float(((unsigned)uh[t * 72 + io]) << 16)
                             + __uint_as_float(((unsigned)ul[t * 72 + io]) << 16);
                    float y = a[r] + Dh * uv;
                    op[r] = (unsigned short)f2bf(gelu_fast(y));
                }
                *(ushort4*)(&orow[t * 64 + w * 16 + g * 4]) = ov;
            }
        }
        __syncthreads();
    }
}

// ---------------- Kernel C: MFMA bf16 GEMM 64x64, double-buffered staging ----------------
__global__ __launch_bounds__(256) void gemm_glu_mfma(const unsigned short* __restrict__ yhi,
                                                     const float* __restrict__ W,
                                                     const unsigned short* __restrict__ whi,
                                                     const float* __restrict__ bias,
                                                     float* __restrict__ out, int preW) {
    const int b = blockIdx.z;
    const int d0 = blockIdx.y * 64;
    const int l0 = blockIdx.x * 64;
    const int tid = threadIdx.x;
    const int lane = tid & 63;
    const int wid = tid >> 6;
    const int wave_m = wid & 1;
    const int wave_n = wid >> 1;
    const int l15 = lane & 15;
    const int g = lane >> 4;

    __shared__ unsigned short Ysh[2][32 * 64];
    __shared__ char Wlds[2][128 * 64];

    f32x4 acc[4][2];
#pragma unroll
    for (int i = 0; i < 4; i++)
#pragma unroll
        for (int j = 0; j < 2; j++) acc[i][j] = (f32x4){0.f, 0.f, 0.f, 0.f};

#define STAGE(BUF, KT)                                                                   \
    {                                                                                    \
        const int h0s = (KT) * 32;                                                       \
        {                                                                                \
            int kr = tid >> 3;                                                           \
            int cc = tid & 7;                                                            \
            int scol = (cc * 8) ^ ((kr & 8) ? 8 : 0);                                    \
            const unsigned short* srcY = yhi + ((size_t)(b * HH + h0s + kr)) * LL + l0 + scol; \
            gload_lds16(srcY, (char*)Ysh[BUF] + tid * 16);                               \
        }                                                                                \
        if (preW) {                                                                      \
            _Pragma("unroll")                                                            \
            for (int e = 0; e < 2; e++) {                                                \
                int c = e * 256 + tid;                                                   \
                int row = c >> 2;                                                        \
                int gx = c & 3;                                                          \
                int qq = (row >> 1) & 3;                                                 \
                int grow = (row < 64) ? (d0 + row) : (448 + d0 + row);                   \
                const unsigned short* srcW = whi + (size_t)grow * 512 + h0s + ((gx ^ qq) * 8); \
                gload_lds16(srcW, Wlds[BUF] + c * 16);                                   \
            }                                                                            \
        } else {                                                                         \
            int row = tid >> 1;                                                          \
            int kb = (tid & 1) * 16;                                                     \
            int qq = (row >> 1) & 3;                                                     \
            int grow = (row < 64) ? (d0 + row) : (448 + d0 + row);                       \
            const float* srcW = W + (size_t)grow * 512 + h0s + kb;                       \
            float4 w0 = *(const float4*)(srcW);                                          \
            float4 w1 = *(const float4*)(srcW + 4);                                      \
            float4 w2 = *(const float4*)(srcW + 8);                                      \
            float4 w3 = *(const float4*)(srcW + 12);                                     \
            short8 v0, v1;                                                               \
            v0[0] = (short)f2bf(w0.x); v0[1] = (short)f2bf(w0.y);                        \
            v0[2] = (short)f2bf(w0.z); v0[3] = (short)f2bf(w0.w);                        \
            v0[4] = (short)f2bf(w1.x); v0[5] = (short)f2bf(w1.y);                        \
            v0[6] = (short)f2bf(w1.z); v0[7] = (short)f2bf(w1.w);                        \
            v1[0] = (short)f2bf(w2.x); v1[1] = (short)f2bf(w2.y);                        \
            v1[2] = (short)f2bf(w2.z); v1[3] = (short)f2bf(w2.w);                        \
            v1[4] = (short)f2bf(w3.x); v1[5] = (short)f2bf(w3.y);                        \
            v1[6] = (short)f2bf(w3.z); v1[7] = (short)f2bf(w3.w);                        \
            int g0 = kb >> 3;                                                            \
            *(short8*)(Wlds[BUF] + row * 64 + ((g0 ^ qq) * 16)) = v0;                    \
            *(short8*)(Wlds[BUF] + row * 64 + (((g0 + 1) ^ qq) * 16)) = v1;              \
        }                                                                                \
    }

    STAGE(0, 0)
    __syncthreads();

    int cur = 0;
    for (int kt = 0; kt < 16; kt++) {
        if (kt < 15) STAGE(cur ^ 1, kt + 1)

        short8 af[4];
#pragma unroll
        for (int mi = 0; mi < 4; mi++) {
            int rowb = (mi < 2) ? (wave_m * 32 + mi * 16) : (64 + wave_m * 32 + (mi - 2) * 16);
            int row = rowb + l15;
            int qq = (row >> 1) & 3;
            af[mi] = *(const short8*)(Wlds[cur] + row * 64 + ((g ^ qq) * 16));
        }
#pragma unroll
        for (int ni = 0; ni < 2; ni++) {
            int col = wave_n * 32 + ni * 16 + l15;
            int cs = col ^ ((g & 1) << 3);
            const unsigned short* yb = Ysh[cur] + (8 * g) * 64 + cs;
            short8 bh;
            bh[0] = (short)yb[0 * 64];
            bh[1] = (short)yb[1 * 64];
            bh[2] = (short)yb[2 * 64];
            bh[3] = (short)yb[3 * 64];
            bh[4] = (short)yb[4 * 64];
            bh[5] = (short)yb[5 * 64];
            bh[6] = (short)yb[6 * 64];
            bh[7] = (short)yb[7 * 64];
#pragma unroll
            for (int mi = 0; mi < 4; mi++) {
                acc[mi][ni] = __builtin_amdgcn_mfma_f32_16x16x32_bf16(af[mi], bh, acc[mi][ni], 0, 0, 0);
            }
        }
        __syncthreads();
        cur ^= 1;
    }
#undef STAGE

#pragma unroll
    for (int mi = 0; mi < 2; mi++) {
        int dbase = d0 + wave_m * 32 + mi * 16 + (g << 2);
#pragma unroll
        for (int r = 0; r < 4; r++) {
            int d = dbase + r;
            float b1 = bias[d], b2 = bias[DMOUT + d];
#pragma unroll
            for (int ni = 0; ni < 2; ni++) {
                int l = l0 + wave_n * 32 + ni * 16 + l15;
                float z1 = acc[mi][ni][r] + b1;
                float z2 = acc[mi + 2][ni][r] + b2;
                out[((size_t)(b * DMOUT + d)) * LL + l] = z1 * (1.0f / (1.0f + __expf(-z2)));
            }
        }
    }
}

extern "C" void kernel_launch(void* const* d_in, const int* in_sizes, int n_in,
                              void* d_out, int out_size, void* d_ws, size_t ws_size,
                              hipStream_t stream) {
    const float* u      = (const float*)d_in[0];
    const float* log_dt = (const float*)d_in[1];
    const float* A_re   = (const float*)d_in[2];
    const float* A_im   = (const float*)d_in[3];
    const float* B_re   = (const float*)d_in[4];
    const float* B_im   = (const float*)d_in[5];
    const float* C_re   = (const float*)d_in[6];
    const float* C_im   = (const float*)d_in[7];
    const float* D      = (const float*)d_in[8];
    const float* W      = (const float*)d_in[9];
    const float* bias   = (const float*)d_in[10];
    float* out = (float*)d_out;

    char* ws = (char*)d_ws;
    unsigned short* yhi = (unsigned short*)ws;                     // 16,777,216 B
    unsigned* A3t = (unsigned*)(ws + 16777216);                    //  8,388,608 B
    unsigned* Et  = (unsigned*)(ws + 16777216 + 8388608);          //  8,388,608 B
    unsigned short* whi = (unsigned short*)(ws + 33554432);        //  1,048,576 B (total 34.6 MB)
    int preW = (ws_size >= (size_t)(33554432 + 1048576)) ? 1 : 0;

    prep_kernel<<<HH, 256, 0, stream>>>(log_dt, A_re, A_im, B_re, B_im, C_re, C_im,
                                        W, A3t, Et, whi, preW);
    ssm_kernel<<<dim3(HH, BB / 2), 256, 0, stream>>>(u, log_dt, A_re, A_im, B_re, B_im,
                                                     C_re, C_im, D, A3t, Et, yhi);
    gemm_glu_mfma<<<dim3(64, 8, BB), 256, 0, stream>>>(yhi, W, whi, bias, out, preW);
}